// Round 1
// baseline (630.422 us; speedup 1.0000x reference)
//
#include <hip/hip_runtime.h>
#include <hip/hip_bf16.h>

// Problem constants
#define T_TOK 4096
#define HID   3584
#define NH    28
#define NKV   4
#define HD    128
#define SEG   4
#define LSEQ  1024
#define KDIM  3584   // K of all GEMMs (HID == NH*HD)

typedef __attribute__((ext_vector_type(8))) short bf16x8;
typedef __attribute__((ext_vector_type(4))) float f32x4;

#define GLOAD16(g, l) __builtin_amdgcn_global_load_lds( \
    (const __attribute__((address_space(1))) void*)(g), \
    (__attribute__((address_space(3))) void*)(l), 16, 0, 0)

__device__ __forceinline__ unsigned short f2bf(float f) {
    unsigned u = __float_as_uint(f);
    return (unsigned short)((u + 0x7fffu + ((u >> 16) & 1u)) >> 16);
}

__device__ __forceinline__ f32x4 mfma16(bf16x8 a, bf16x8 b, f32x4 c) {
    return __builtin_amdgcn_mfma_f32_16x16x32_bf16(a, b, c, 0, 0, 0);
}

// ---------------- conversion kernels ----------------

// straight f32 -> bf16 (n4 = n/4 float4 chunks)
__global__ void cvt_f32_bf16(const float* __restrict__ s, unsigned short* __restrict__ d, int n4) {
    int i = blockIdx.x * 256 + threadIdx.x;
    if (i >= n4) return;
    float4 v = reinterpret_cast<const float4*>(s)[i];
    ushort4 o;
    o.x = f2bf(v.x); o.y = f2bf(v.y); o.z = f2bf(v.z); o.w = f2bf(v.w);
    reinterpret_cast<ushort4*>(d)[i] = o;
}

// x (T,HID) f32 -> parity-compacted bf16: xu[i]=x[2i], xg[i]=x[2i+1]
__global__ void cvt_x_split(const float* __restrict__ x,
                            unsigned short* __restrict__ xu, unsigned short* __restrict__ xg) {
    int i = blockIdx.x * 256 + threadIdx.x;     // over T*HID/4
    int t = i / (HID / 4);
    int c = i - t * (HID / 4);
    float4 v = reinterpret_cast<const float4*>(x)[i];
    ushort4 o;
    o.x = f2bf(v.x); o.y = f2bf(v.y); o.z = f2bf(v.z); o.w = f2bf(v.w);
    unsigned short* dst = ((t & 1) ? xg : xu) + (size_t)(t >> 1) * HID + c * 4;
    *reinterpret_cast<ushort4*>(dst) = o;
}

// ---------------- GEMM core (128x128 tile, BK=32, dbuf, global_load_lds) ----------------
// A: (M,K) bf16 row-major (pre-offset to this block's 128 rows)
// B: (N,K) bf16 row-major (weights, pre-offset to this block's 128 rows) -> C = A @ B^T
// LDS tiles stored with 2-bit chunk XOR swizzle (rows are 64B = 4x16B chunks).
__device__ __forceinline__ void gemm_core_128(const unsigned short* __restrict__ A,
                                              const unsigned short* __restrict__ B,
                                              unsigned short* lds, f32x4 (&acc)[4][4]) {
    const int tid = threadIdx.x;
    const int lane = tid & 63;
    const int wave = tid >> 6, wr = wave >> 1, wc = wave & 1;
    const int lr = lane & 15, lkg = lane >> 4;

#pragma unroll
    for (int m = 0; m < 4; m++)
#pragma unroll
        for (int n = 0; n < 4; n++) acc[m][n] = (f32x4){0.f, 0.f, 0.f, 0.f};

    auto stage = [&](int buf, int k0) {
        char* lbase = (char*)lds + buf * 16384;
#pragma unroll
        for (int i = 0; i < 2; i++) {
            int o = i * 4096 + tid * 16;                 // byte offset in 8KB tile
            int r = o >> 6;                              // row (64B rows)
            int sc = ((o >> 4) & 3) ^ (r & 3);           // swizzled source chunk
            GLOAD16(A + (size_t)r * KDIM + k0 + sc * 8, lbase + o);
            GLOAD16(B + (size_t)r * KDIM + k0 + sc * 8, lbase + 8192 + o);
        }
    };

    stage(0, 0);
    __syncthreads();
    int cur = 0;
    for (int t = 0; t < KDIM / 32; ++t) {
        if (t + 1 < KDIM / 32) stage(cur ^ 1, (t + 1) * 32);
        const char* la = (const char*)lds + cur * 16384;
        const char* lb = la + 8192;
        bf16x8 af[4], bfr[4];
#pragma unroll
        for (int m = 0; m < 4; m++) {
            int r = wr * 64 + m * 16 + lr;
            af[m] = *(const bf16x8*)(la + r * 64 + ((lkg ^ (r & 3)) << 4));
        }
#pragma unroll
        for (int n = 0; n < 4; n++) {
            int r = wc * 64 + n * 16 + lr;
            bfr[n] = *(const bf16x8*)(lb + r * 64 + ((lkg ^ (r & 3)) << 4));
        }
#pragma unroll
        for (int m = 0; m < 4; m++)
#pragma unroll
            for (int n = 0; n < 4; n++)
                acc[m][n] = mfma16(af[m], bfr[n], acc[m][n]);
        __syncthreads();
        cur ^= 1;
    }
}

// ---------------- fused QKV projection ----------------
// grid: (16 mblocks, 36 nblocks [28 q | 4 k | 4 v], 2 parity)
__global__ __launch_bounds__(256, 2) void qkv_gemm(
    const unsigned short* __restrict__ xu, const unsigned short* __restrict__ xg,
    const unsigned short* __restrict__ wq0, const unsigned short* __restrict__ wk0,
    const unsigned short* __restrict__ wv0, const unsigned short* __restrict__ wq1,
    const unsigned short* __restrict__ wk1, const unsigned short* __restrict__ wv1,
    const float* __restrict__ bq0, const float* __restrict__ bk0, const float* __restrict__ bv0,
    const float* __restrict__ bq1, const float* __restrict__ bk1, const float* __restrict__ bv1,
    float* __restrict__ qo, float* __restrict__ ko, float* __restrict__ vo) {
    __shared__ unsigned short lds[2 * 2 * 4096];
    const int bm = blockIdx.x, nb = blockIdx.y, par = blockIdx.z;
    const unsigned short* A = (par ? xg : xu) + (size_t)bm * 128 * KDIM;
    const unsigned short* W;
    const float* bias;
    float* C;
    int ldc, ncol0;
    if (nb < 28) {
        W = (par ? wq1 : wq0) + (size_t)nb * 128 * KDIM;
        bias = (par ? bq1 : bq0) + nb * 128;
        C = qo; ldc = NH * HD; ncol0 = nb * 128;
    } else if (nb < 32) {
        int j = nb - 28;
        W = (par ? wk1 : wk0) + (size_t)j * 128 * KDIM;
        bias = (par ? bk1 : bk0) + j * 128;
        C = ko; ldc = NKV * HD; ncol0 = j * 128;
    } else {
        int j = nb - 32;
        W = (par ? wv1 : wv0) + (size_t)j * 128 * KDIM;
        bias = (par ? bv1 : bv0) + j * 128;
        C = vo; ldc = NKV * HD; ncol0 = j * 128;
    }
    f32x4 acc[4][4];
    gemm_core_128(A, W, lds, acc);

    const int lane = threadIdx.x & 63, wave = threadIdx.x >> 6;
    const int wr = wave >> 1, wc = wave & 1, lr = lane & 15, lkg = lane >> 4;
#pragma unroll
    for (int n = 0; n < 4; n++) {
        int colt = wc * 64 + n * 16 + lr;
        float bb = bias[colt];
#pragma unroll
        for (int m = 0; m < 4; m++) {
#pragma unroll
            for (int rg = 0; rg < 4; rg++) {
                int rt = wr * 64 + m * 16 + lkg * 4 + rg;
                int t = 2 * (bm * 128 + rt) + par;     // interleave parity back
                C[(size_t)t * ldc + ncol0 + colt] = acc[m][n][rg] + bb;
            }
        }
    }
}

// ---------------- RMSNorm + RoPE (+ V transpose/convert) ----------------
// grid: (T, 36) block 128. h<28: q head; 28..31: k head; 32..35: v head (transpose only)
__global__ void normrope(const float* __restrict__ q, const float* __restrict__ k,
                         const float* __restrict__ v,
                         const float* __restrict__ cosb, const float* __restrict__ sinb,
                         const float* __restrict__ qn, const float* __restrict__ kn,
                         const float* __restrict__ qng, const float* __restrict__ kng,
                         unsigned short* __restrict__ q_bf, unsigned short* __restrict__ k_bf,
                         unsigned short* __restrict__ vT) {
    const int t = blockIdx.x, h = blockIdx.y, d = threadIdx.x;
    if (h >= 32) {  // V path: write vT[(s*NKV+hv)*HD + d][l]
        int hv = h - 32;
        float val = v[(size_t)t * (NKV * HD) + hv * HD + d];
        int s = t >> 10, l = t & 1023;
        vT[((size_t)(s * NKV + hv) * HD + d) * LSEQ + l] = f2bf(val);
        return;
    }
    const bool isq = (h < 28);
    float val = isq ? q[(size_t)t * (NH * HD) + h * HD + d]
                    : k[(size_t)t * (NKV * HD) + (h - 28) * HD + d];
    float ss = val * val;
#pragma unroll
    for (int off = 32; off >= 1; off >>= 1) ss += __shfl_xor(ss, off, 64);
    __shared__ float wsum[2];
    __shared__ float rowbuf[128];
    if ((threadIdx.x & 63) == 0) wsum[threadIdx.x >> 6] = ss;
    __syncthreads();
    float inv = rsqrtf((wsum[0] + wsum[1]) * (1.f / 128.f) + 1e-6f);
    const float* wn = isq ? ((t & 1) ? qng : qn) : ((t & 1) ? kng : kn);
    float nv = val * inv * wn[d];
    rowbuf[d] = nv;
    __syncthreads();
    float rot = (d < 64) ? -rowbuf[d + 64] : rowbuf[d - 64];
    float o = nv * cosb[(size_t)t * HD + d] + rot * sinb[(size_t)t * HD + d];
    if (isq) q_bf[(size_t)t * (NH * HD) + h * HD + d] = f2bf(o);
    else     k_bf[(size_t)t * (NKV * HD) + (h - 28) * HD + d] = f2bf(o);
}

// ---------------- flash attention ----------------
// grid: (16 qblocks of 64, 28 heads, 4 segments), 256 threads (4 waves x 16 q rows)
__global__ __launch_bounds__(256, 2) void attn_fwd(
    const unsigned short* __restrict__ q_bf, const unsigned short* __restrict__ k_bf,
    const unsigned short* __restrict__ vT,
    unsigned short* __restrict__ au, unsigned short* __restrict__ ag) {
    __shared__ unsigned short kt[64 * 128];   // K tile  [kv(64)][d(128)]  swizzled, 16KB
    __shared__ unsigned short vt[128 * 64];   // V tile  [d(128)][kv(64)]  swizzled, 16KB
    __shared__ unsigned short pt[4][16 * 64]; // per-wave P [q(16)][kv(64)] swizzled, 8KB

    const int qbk = blockIdx.x, h = blockIdx.y, s = blockIdx.z;
    const int hk = h / 7;   // GQA group of 7
    const int tid = threadIdx.x, lane = tid & 63, w = tid >> 6;
    const int lr = lane & 15, lkg = lane >> 4;

    // Q fragments in registers (16 rows per wave, K=128 -> 4 frags)
    bf16x8 qf[4];
    {
        const unsigned short* qp =
            q_bf + ((size_t)(s * LSEQ + qbk * 64 + w * 16 + lr)) * (NH * HD) + h * HD;
#pragma unroll
        for (int kk = 0; kk < 4; kk++) qf[kk] = *(const bf16x8*)(qp + kk * 32 + lkg * 8);
    }

    float m_r[4] = {-1e30f, -1e30f, -1e30f, -1e30f};
    float l_r[4] = {0.f, 0.f, 0.f, 0.f};
    f32x4 accO[8];
#pragma unroll
    for (int dn = 0; dn < 8; dn++) accO[dn] = (f32x4){0.f, 0.f, 0.f, 0.f};

    const float scale = 0.08838834764831843f;   // 1/sqrt(128)
    const int nkt = qbk + 1;                    // causal: kv tiles of 64 up to this q block

    for (int ktile = 0; ktile < nkt; ++ktile) {
        __syncthreads();   // prior tile's LDS reads drained before restage
        // stage K (64x128) and V^T (128x64), 3-bit chunk XOR swizzle via source addr
#pragma unroll
        for (int i = 0; i < 4; i++) {
            int o = i * 4096 + tid * 16;
            {   // K: rows 256B = 16 chunks
                int r = o >> 8;
                int sc = ((o >> 4) & 15) ^ (r & 7);
                GLOAD16(k_bf + ((size_t)(s * LSEQ + ktile * 64 + r)) * (NKV * HD) + hk * HD + sc * 8,
                        (char*)kt + o);
            }
            {   // V^T: rows 128B = 8 chunks
                int r = o >> 7;
                int sc = ((o >> 4) & 7) ^ (r & 7);
                GLOAD16(vT + ((size_t)((s * NKV + hk) * HD + r)) * LSEQ + ktile * 64 + sc * 8,
                        (char*)vt + o);
            }
        }
        __syncthreads();

        // S = Q K^T   (16 q rows x 64 kv cols per wave)
        f32x4 accS[4];
#pragma unroll
        for (int n = 0; n < 4; n++) accS[n] = (f32x4){0.f, 0.f, 0.f, 0.f};
#pragma unroll
        for (int n = 0; n < 4; n++) {
            int r = n * 16 + lr;
#pragma unroll
            for (int kk = 0; kk < 4; kk++) {
                bf16x8 kf = *(const bf16x8*)((const char*)kt + r * 256 +
                                             (((kk * 4 + lkg) ^ (r & 7)) << 4));
                accS[n] = mfma16(qf[kk], kf, accS[n]);
            }
        }
        // scale + causal mask + per-row max
        float mnew[4] = {-1e30f, -1e30f, -1e30f, -1e30f};
#pragma unroll
        for (int n = 0; n < 4; n++) {
            int col = ktile * 64 + n * 16 + lr;
#pragma unroll
            for (int rg = 0; rg < 4; rg++) {
                int row = qbk * 64 + w * 16 + lkg * 4 + rg;
                float sv = accS[n][rg] * scale;
                sv = (col <= row) ? sv : -1e30f;
                accS[n][rg] = sv;
                mnew[rg] = fmaxf(mnew[rg], sv);
            }
        }
#pragma unroll
        for (int off = 1; off < 16; off <<= 1)
#pragma unroll
            for (int rg = 0; rg < 4; rg++)
                mnew[rg] = fmaxf(mnew[rg], __shfl_xor(mnew[rg], off, 64));
        // online softmax update
        float alpha[4];
#pragma unroll
        for (int rg = 0; rg < 4; rg++) {
            float mc = fmaxf(m_r[rg], mnew[rg]);
            alpha[rg] = __expf(m_r[rg] - mc);
            m_r[rg] = mc;
            l_r[rg] *= alpha[rg];
        }
#pragma unroll
        for (int dn = 0; dn < 8; dn++)
#pragma unroll
            for (int rg = 0; rg < 4; rg++) accO[dn][rg] *= alpha[rg];
        // P = exp(S-m): row sums + bf16 P to per-wave LDS (swizzled)
        float ls[4] = {0.f, 0.f, 0.f, 0.f};
#pragma unroll
        for (int n = 0; n < 4; n++) {
#pragma unroll
            for (int rg = 0; rg < 4; rg++) {
                float p = __expf(accS[n][rg] - m_r[rg]);
                ls[rg] += p;
                int pr = lkg * 4 + rg;
                *(unsigned short*)((char*)pt[w] + pr * 128 +
                                   (((n * 16 + lr) * 2) ^ ((pr & 7) << 4))) = f2bf(p);
            }
        }
#pragma unroll
        for (int off = 1; off < 16; off <<= 1)
#pragma unroll
            for (int rg = 0; rg < 4; rg++) ls[rg] += __shfl_xor(ls[rg], off, 64);
#pragma unroll
        for (int rg = 0; rg < 4; rg++) l_r[rg] += ls[rg];
        // O += P V
#pragma unroll
        for (int kk2 = 0; kk2 < 2; kk2++) {
            bf16x8 pf = *(const bf16x8*)((const char*)pt[w] + lr * 128 +
                                         (((kk2 * 4 + lkg) ^ (lr & 7)) << 4));
#pragma unroll
            for (int dn = 0; dn < 8; dn++) {
                int r2 = dn * 16 + lr;
                bf16x8 vf = *(const bf16x8*)((const char*)vt + r2 * 128 +
                                             (((kk2 * 4 + lkg) ^ (r2 & 7)) << 4));
                accO[dn] = mfma16(pf, vf, accO[dn]);
            }
        }
    }
    // epilogue: O / l, parity-compacted bf16 for the O-projection GEMM
#pragma unroll
    for (int dn = 0; dn < 8; dn++) {
#pragma unroll
        for (int rg = 0; rg < 4; rg++) {
            int row = qbk * 64 + w * 16 + lkg * 4 + rg;
            int t = s * LSEQ + row;
            unsigned short* dst = ((t & 1) ? ag : au) + (size_t)(t >> 1) * (NH * HD) +
                                  h * HD + dn * 16 + lr;
            *dst = f2bf(accO[dn][rg] / l_r[rg]);
        }
    }
}

// ---------------- output projection ----------------
__global__ __launch_bounds__(256, 2) void oproj_gemm(
    const unsigned short* __restrict__ au, const unsigned short* __restrict__ ag,
    const unsigned short* __restrict__ wo0, const unsigned short* __restrict__ wo1,
    float* __restrict__ out) {
    __shared__ unsigned short lds[2 * 2 * 4096];
    const int bm = blockIdx.x, nb = blockIdx.y, par = blockIdx.z;
    const unsigned short* A = (par ? ag : au) + (size_t)bm * 128 * KDIM;
    const unsigned short* W = (par ? wo1 : wo0) + (size_t)nb * 128 * KDIM;
    f32x4 acc[4][4];
    gemm_core_128(A, W, lds, acc);

    const int lane = threadIdx.x & 63, wave = threadIdx.x >> 6;
    const int wr = wave >> 1, wc = wave & 1, lr = lane & 15, lkg = lane >> 4;
#pragma unroll
    for (int n = 0; n < 4; n++) {
        int col = nb * 128 + wc * 64 + n * 16 + lr;
#pragma unroll
        for (int m = 0; m < 4; m++) {
#pragma unroll
            for (int rg = 0; rg < 4; rg++) {
                int rt = wr * 64 + m * 16 + lkg * 4 + rg;
                int t = 2 * (bm * 128 + rt) + par;
                out[(size_t)t * HID + col] = acc[m][n][rg];
            }
        }
    }
}

// ---------------- host ----------------
extern "C" void kernel_launch(void* const* d_in, const int* in_sizes, int n_in,
                              void* d_out, int out_size, void* d_ws, size_t ws_size,
                              hipStream_t stream) {
    const float* x    = (const float*)d_in[0];
    const float* cosb = (const float*)d_in[1];
    const float* sinb = (const float*)d_in[2];
    const float* wq   = (const float*)d_in[3];
    const float* bq   = (const float*)d_in[4];
    const float* wk   = (const float*)d_in[5];
    const float* bk   = (const float*)d_in[6];
    const float* wv   = (const float*)d_in[7];
    const float* bv   = (const float*)d_in[8];
    const float* wo   = (const float*)d_in[9];
    const float* wqg  = (const float*)d_in[10];
    const float* bqg  = (const float*)d_in[11];
    const float* wkg  = (const float*)d_in[12];
    const float* bkg  = (const float*)d_in[13];
    const float* wvg  = (const float*)d_in[14];
    const float* bvg  = (const float*)d_in[15];
    const float* wog  = (const float*)d_in[16];
    const float* qn   = (const float*)d_in[17];
    const float* kn   = (const float*)d_in[18];
    const float* qng  = (const float*)d_in[19];
    const float* kng  = (const float*)d_in[20];
    float* out = (float*)d_out;

    // workspace layout (all sizes 256B-aligned already); total ~248 MiB
    char* ws = (char*)d_ws;
    size_t off = 0;
    auto alloc = [&](size_t bytes) -> char* {
        char* p = ws + off;
        off += (bytes + 255) & ~(size_t)255;
        return p;
    };
    const size_t WQ_E = (size_t)3584 * 3584;   // q/o weight elems
    const size_t WK_E = (size_t)512 * 3584;    // k/v weight elems
    unsigned short* wqb  = (unsigned short*)alloc(WQ_E * 2);
    unsigned short* wqgb = (unsigned short*)alloc(WQ_E * 2);
    unsigned short* wob  = (unsigned short*)alloc(WQ_E * 2);
    unsigned short* wogb = (unsigned short*)alloc(WQ_E * 2);
    unsigned short* wkb  = (unsigned short*)alloc(WK_E * 2);
    unsigned short* wkgb = (unsigned short*)alloc(WK_E * 2);
    unsigned short* wvb  = (unsigned short*)alloc(WK_E * 2);
    unsigned short* wvgb = (unsigned short*)alloc(WK_E * 2);
    unsigned short* xu   = (unsigned short*)alloc((size_t)2048 * HID * 2);
    unsigned short* xg   = (unsigned short*)alloc((size_t)2048 * HID * 2);
    float* qf32 = (float*)alloc((size_t)T_TOK * (NH * HD) * 4);   // dead after normrope
    float* kf32 = (float*)alloc((size_t)T_TOK * (NKV * HD) * 4);
    float* vf32 = (float*)alloc((size_t)T_TOK * (NKV * HD) * 4);
    unsigned short* q_bf = (unsigned short*)alloc((size_t)T_TOK * (NH * HD) * 2);
    unsigned short* k_bf = (unsigned short*)alloc((size_t)T_TOK * (NKV * HD) * 2);
    unsigned short* vTb  = (unsigned short*)alloc((size_t)SEG * NKV * HD * LSEQ * 2);
    // attn output aliases the (dead) qf32 region: 29.4MB fits in 58.7MB
    unsigned short* au = (unsigned short*)qf32;
    unsigned short* ag = au + (size_t)2048 * (NH * HD);

    if (ws_size < off) return;   // insufficient workspace -> leave output poisoned

    // 1) conversions
    cvt_x_split<<<T_TOK * (HID / 4) / 256, 256, 0, stream>>>(x, xu, xg);
    cvt_f32_bf16<<<(int)(WQ_E / 4 / 256), 256, 0, stream>>>(wq,  wqb,  (int)(WQ_E / 4));
    cvt_f32_bf16<<<(int)(WQ_E / 4 / 256), 256, 0, stream>>>(wqg, wqgb, (int)(WQ_E / 4));
    cvt_f32_bf16<<<(int)(WQ_E / 4 / 256), 256, 0, stream>>>(wo,  wob,  (int)(WQ_E / 4));
    cvt_f32_bf16<<<(int)(WQ_E / 4 / 256), 256, 0, stream>>>(wog, wogb, (int)(WQ_E / 4));
    cvt_f32_bf16<<<(int)(WK_E / 4 / 256), 256, 0, stream>>>(wk,  wkb,  (int)(WK_E / 4));
    cvt_f32_bf16<<<(int)(WK_E / 4 / 256), 256, 0, stream>>>(wkg, wkgb, (int)(WK_E / 4));
    cvt_f32_bf16<<<(int)(WK_E / 4 / 256), 256, 0, stream>>>(wv,  wvb,  (int)(WK_E / 4));
    cvt_f32_bf16<<<(int)(WK_E / 4 / 256), 256, 0, stream>>>(wvg, wvgb, (int)(WK_E / 4));
    // 2) QKV projection (+bias), parity-routed
    qkv_gemm<<<dim3(16, 36, 2), 256, 0, stream>>>(xu, xg, wqb, wkb, wvb, wqgb, wkgb, wvgb,
                                                  bq, bk, bv, bqg, bkg, bvg, qf32, kf32, vf32);
    // 3) RMSNorm + RoPE (q,k) and V transpose/convert
    normrope<<<dim3(T_TOK, 36), 128, 0, stream>>>(qf32, kf32, vf32, cosb, sinb,
                                                  qn, kn, qng, kng, q_bf, k_bf, vTb);
    // 4) causal GQA flash attention
    attn_fwd<<<dim3(16, NH, SEG), 256, 0, stream>>>(q_bf, k_bf, vTb, au, ag);
    // 5) output projection, parity-routed
    oproj_gemm<<<dim3(16, 28, 2), 256, 0, stream>>>(au, ag, wob, wogb, out);
}

// Round 2
// 579.505 us; speedup vs baseline: 1.0879x; 1.0879x over previous
//
#include <hip/hip_runtime.h>
#include <hip/hip_bf16.h>

// Problem constants
#define T_TOK 4096
#define HID   3584
#define NH    28
#define NKV   4
#define HD    128
#define SEG   4
#define LSEQ  1024
#define KDIM  3584   // K of all GEMMs (HID == NH*HD)
#define BKG   64     // GEMM K-tile

typedef __attribute__((ext_vector_type(8))) short bf16x8;
typedef __attribute__((ext_vector_type(4))) float f32x4;

#define GLOAD16(g, l) __builtin_amdgcn_global_load_lds( \
    (const __attribute__((address_space(1))) void*)(g), \
    (__attribute__((address_space(3))) void*)(l), 16, 0, 0)

__device__ __forceinline__ unsigned short f2bf(float f) {
    unsigned u = __float_as_uint(f);
    return (unsigned short)((u + 0x7fffu + ((u >> 16) & 1u)) >> 16);
}

__device__ __forceinline__ f32x4 mfma16(bf16x8 a, bf16x8 b, f32x4 c) {
    return __builtin_amdgcn_mfma_f32_16x16x32_bf16(a, b, c, 0, 0, 0);
}

// ---------------- conversion kernels ----------------

__global__ void cvt_f32_bf16(const float* __restrict__ s, unsigned short* __restrict__ d, int n4) {
    int i = blockIdx.x * 256 + threadIdx.x;
    if (i >= n4) return;
    float4 v = reinterpret_cast<const float4*>(s)[i];
    ushort4 o;
    o.x = f2bf(v.x); o.y = f2bf(v.y); o.z = f2bf(v.z); o.w = f2bf(v.w);
    reinterpret_cast<ushort4*>(d)[i] = o;
}

__global__ void cvt_x_split(const float* __restrict__ x,
                            unsigned short* __restrict__ xu, unsigned short* __restrict__ xg) {
    int i = blockIdx.x * 256 + threadIdx.x;     // over T*HID/4
    int t = i / (HID / 4);
    int c = i - t * (HID / 4);
    float4 v = reinterpret_cast<const float4*>(x)[i];
    ushort4 o;
    o.x = f2bf(v.x); o.y = f2bf(v.y); o.z = f2bf(v.z); o.w = f2bf(v.w);
    unsigned short* dst = ((t & 1) ? xg : xu) + (size_t)(t >> 1) * HID + c * 4;
    *reinterpret_cast<ushort4*>(dst) = o;
}

// ---------------- 256x256 8-phase GEMM core ----------------
// A: 256 rows x KDIM bf16 row-major (pre-offset). B: 256 rows x KDIM (weights, C = A@B^T).
// LDS: 2 bufs x (A 32KB + B 32KB) = 128KB. Rows 128B = 8 chunks of 16B,
// phys_chunk = log_chunk ^ (row&7) (written via pre-swizzled global source).
__device__ __forceinline__ void gemm256_core(const unsigned short* __restrict__ Aptr,
                                             const unsigned short* __restrict__ Bptr,
                                             unsigned short* ldsbase, f32x4 (&acc)[8][4]) {
    const int tid = threadIdx.x;               // 0..511
    const int lane = tid & 63, w = tid >> 6;
    const int wr = w >> 2, wc = w & 3;         // wave grid 2M x 4N
    const int lr = lane & 15, lkg = lane >> 4;
    char* const L = (char*)ldsbase;

    // staging source offsets: stage-call j covers 64 rows (8KB); dest linear tid*16.
    // dest o = j*8192 + tid*16 -> r = j*64 + tid/8, phys chunk = tid&7,
    // log chunk = (tid&7) ^ (r&7)  (pre-swizzled source, linear LDS dest)
    int src_off[4];
#pragma unroll
    for (int j = 0; j < 4; j++) {
        int r = j * 64 + (tid >> 3);
        int clog = (tid & 7) ^ ((tid >> 3) & 7);
        src_off[j] = r * KDIM + clog * 8;
    }
    // ds_read frag base offsets (row&7 == lr&7 since 16-row strides are 8-aligned)
    const int aoff0 = (wr * 128 + lr) * 128 + ((lkg ^ (lr & 7)) << 4);
    const int boff0 = (wc * 64 + lr) * 128 + ((lkg ^ (lr & 7)) << 4) + 32768;

    bf16x8 a[4][2], b[4][2];
#pragma unroll
    for (int m = 0; m < 8; m++)
#pragma unroll
        for (int n = 0; n < 4; n++) acc[m][n] = (f32x4){0.f, 0.f, 0.f, 0.f};

#define STG_A(buf, k0, h) do { _Pragma("unroll") for (int jj = 0; jj < 2; jj++) { \
    int j = (h) * 2 + jj; \
    GLOAD16(Aptr + src_off[j] + (k0), L + (buf) * 65536 + j * 8192 + tid * 16); } } while (0)
#define STG_B(buf, k0, h) do { _Pragma("unroll") for (int jj = 0; jj < 2; jj++) { \
    int j = (h) * 2 + jj; \
    GLOAD16(Bptr + src_off[j] + (k0), L + (buf) * 65536 + 32768 + j * 8192 + tid * 16); } } while (0)
#define RD_A(buf, mh) do { _Pragma("unroll") for (int mm = 0; mm < 4; mm++) { \
    int ro = (buf) * 65536 + aoff0 + ((mh) * 4 + mm) * 2048; \
    a[mm][0] = *(const bf16x8*)(L + ro); \
    a[mm][1] = *(const bf16x8*)(L + (ro ^ 64)); } } while (0)
#define RD_B(buf, nh) do { _Pragma("unroll") for (int nn = 0; nn < 2; nn++) { \
    int ro = (buf) * 65536 + boff0 + ((nh) * 2 + nn) * 2048; \
    b[(nh) * 2 + nn][0] = *(const bf16x8*)(L + ro); \
    b[(nh) * 2 + nn][1] = *(const bf16x8*)(L + (ro ^ 64)); } } while (0)
#define MM(mh, nh) do { _Pragma("unroll") for (int mm = 0; mm < 4; mm++) \
    _Pragma("unroll") for (int nn = 0; nn < 2; nn++) \
    _Pragma("unroll") for (int ks = 0; ks < 2; ks++) \
        acc[(mh) * 4 + mm][(nh) * 2 + nn] = \
            mfma16(a[mm][ks], b[(nh) * 2 + nn][ks], acc[(mh) * 4 + mm][(nh) * 2 + nn]); } while (0)
#define BAR   asm volatile("s_barrier" ::: "memory")
#define LGKM0 do { asm volatile("s_waitcnt lgkmcnt(0)" ::: "memory"); \
                   __builtin_amdgcn_sched_barrier(0); } while (0)
#define VMC4  asm volatile("s_waitcnt vmcnt(4)" ::: "memory")
#define PHI   __builtin_amdgcn_s_setprio(1)
#define PLO   __builtin_amdgcn_s_setprio(0)

    // prologue: buf0 = tile0 (A+B), buf1.B = tile1's B. buf1.A staged in iter0 P1/P2.
    STG_A(0, 0, 0); STG_A(0, 0, 1); STG_B(0, 0, 0); STG_B(0, 0, 1);
    STG_B(1, BKG, 0); STG_B(1, BKG, 1);
    VMC4;   // 12 issued, wait <=4 outstanding -> buf0's 8 landed
    BAR;

#pragma unroll 1
    for (int t = 0; t < KDIM / (2 * BKG); ++t) {
        int k1 = (2 * t + 1) * BKG;                       // buf1.A tile (this iter's P5-P8)
        int k2 = (2 * t + 2) * BKG; if (k2 > KDIM - BKG) k2 = KDIM - BKG;  // buf0 next
        int k3 = (2 * t + 3) * BKG; if (k3 > KDIM - BKG) k3 = KDIM - BKG;  // buf1.B next
        // P1: compute buf0 (m0-3 x n0-1)
        RD_A(0, 0); RD_B(0, 0); STG_A(1, k1, 0);
        BAR; LGKM0; PHI; MM(0, 0); PLO; BAR;
        // P2: (m0-3 x n2-3)
        RD_B(0, 1); STG_A(1, k1, 1);
        BAR; LGKM0; PHI; MM(0, 1); PLO; BAR;
        // P3: (m4-7 x n0-1); buf0.B reads done -> stage next buf0.B
        RD_A(0, 1); STG_B(0, k2, 0);
        BAR; LGKM0; PHI; MM(1, 0); PLO; BAR;
        // P4: (m4-7 x n2-3); counted wait -> buf1 (P1/P2 A + prev B) landed
        STG_B(0, k2, 1);
        BAR; LGKM0; PHI; MM(1, 1); PLO; VMC4; BAR;
        // P5: compute buf1 (m0-3 x n0-1); buf0.A reads done -> stage next buf0.A
        RD_A(1, 0); RD_B(1, 0); STG_A(0, k2, 0);
        BAR; LGKM0; PHI; MM(0, 0); PLO; BAR;
        // P6
        RD_B(1, 1); STG_A(0, k2, 1);
        BAR; LGKM0; PHI; MM(0, 1); PLO; BAR;
        // P7: buf1.B reads done -> stage next buf1.B
        RD_A(1, 1); STG_B(1, k3, 0);
        BAR; LGKM0; PHI; MM(1, 0); PLO; BAR;
        // P8: counted wait -> buf0 (P3-P6) landed for next iter's P1
        STG_B(1, k3, 1);
        BAR; LGKM0; PHI; MM(1, 1); PLO; VMC4; BAR;
    }
    asm volatile("s_waitcnt vmcnt(0)" ::: "memory");

#undef STG_A
#undef STG_B
#undef RD_A
#undef RD_B
#undef MM
#undef BAR
#undef LGKM0
#undef VMC4
#undef PHI
#undef PLO
}

// ---------------- fused QKV projection (8-phase 256^2) ----------------
// grid: (16 mblocks [0-7 par0 | 8-15 par1], 18 nblocks [14 q | 2 k | 2 v]), 512 thr
__global__ __launch_bounds__(512, 2) void qkv_gemm8(
    const unsigned short* __restrict__ xu, const unsigned short* __restrict__ xg,
    const unsigned short* __restrict__ wq0, const unsigned short* __restrict__ wk0,
    const unsigned short* __restrict__ wv0, const unsigned short* __restrict__ wq1,
    const unsigned short* __restrict__ wk1, const unsigned short* __restrict__ wv1,
    const float* __restrict__ bq0, const float* __restrict__ bk0, const float* __restrict__ bv0,
    const float* __restrict__ bq1, const float* __restrict__ bk1, const float* __restrict__ bv1,
    float* __restrict__ qo, float* __restrict__ ko, float* __restrict__ vo) {
    __shared__ unsigned short lds[65536];   // 128 KiB
    const int bm = blockIdx.x, nb = blockIdx.y;
    const int par = bm >> 3, mb = bm & 7;
    const unsigned short* A = (par ? xg : xu) + (size_t)mb * 256 * KDIM;
    const unsigned short* W;
    const float* bias;
    float* C;
    int ldc, col0;
    if (nb < 14) {
        W = (par ? wq1 : wq0) + (size_t)nb * 256 * KDIM;
        bias = (par ? bq1 : bq0); C = qo; ldc = NH * HD; col0 = nb * 256;
    } else if (nb < 16) {
        W = (par ? wk1 : wk0) + (size_t)(nb - 14) * 256 * KDIM;
        bias = (par ? bk1 : bk0); C = ko; ldc = NKV * HD; col0 = (nb - 14) * 256;
    } else {
        W = (par ? wv1 : wv0) + (size_t)(nb - 16) * 256 * KDIM;
        bias = (par ? bv1 : bv0); C = vo; ldc = NKV * HD; col0 = (nb - 16) * 256;
    }
    f32x4 acc[8][4];
    gemm256_core(A, W, lds, acc);

    const int lane = threadIdx.x & 63, w = threadIdx.x >> 6;
    const int wr = w >> 2, wc = w & 3, lr = lane & 15, lkg = lane >> 4;
#pragma unroll
    for (int n = 0; n < 4; n++) {
        int colt = col0 + wc * 64 + n * 16 + lr;
        float bb = bias[colt];
#pragma unroll
        for (int m = 0; m < 8; m++) {
#pragma unroll
            for (int rg = 0; rg < 4; rg++) {
                int tr = mb * 256 + wr * 128 + m * 16 + lkg * 4 + rg;
                int tok = 2 * tr + par;
                C[(size_t)tok * ldc + colt] = acc[m][n][rg] + bb;
            }
        }
    }
}

// ---------------- output projection (8-phase 256^2) ----------------
__global__ __launch_bounds__(512, 2) void oproj_gemm8(
    const unsigned short* __restrict__ au, const unsigned short* __restrict__ ag,
    const unsigned short* __restrict__ wo0, const unsigned short* __restrict__ wo1,
    float* __restrict__ out) {
    __shared__ unsigned short lds[65536];
    const int bm = blockIdx.x, nb = blockIdx.y;
    const int par = bm >> 3, mb = bm & 7;
    const unsigned short* A = (par ? ag : au) + (size_t)mb * 256 * KDIM;
    const unsigned short* W = (par ? wo1 : wo0) + (size_t)nb * 256 * KDIM;
    f32x4 acc[8][4];
    gemm256_core(A, W, lds, acc);

    const int lane = threadIdx.x & 63, w = threadIdx.x >> 6;
    const int wr = w >> 2, wc = w & 3, lr = lane & 15, lkg = lane >> 4;
#pragma unroll
    for (int n = 0; n < 4; n++) {
        int col = nb * 256 + wc * 64 + n * 16 + lr;
#pragma unroll
        for (int m = 0; m < 8; m++) {
#pragma unroll
            for (int rg = 0; rg < 4; rg++) {
                int tr = mb * 256 + wr * 128 + m * 16 + lkg * 4 + rg;
                int tok = 2 * tr + par;
                out[(size_t)tok * HID + col] = acc[m][n][rg];
            }
        }
    }
}

// ---------------- RMSNorm + RoPE (+ V transpose/convert) ----------------
__global__ void normrope(const float* __restrict__ q, const float* __restrict__ k,
                         const float* __restrict__ v,
                         const float* __restrict__ cosb, const float* __restrict__ sinb,
                         const float* __restrict__ qn, const float* __restrict__ kn,
                         const float* __restrict__ qng, const float* __restrict__ kng,
                         unsigned short* __restrict__ q_bf, unsigned short* __restrict__ k_bf,
                         unsigned short* __restrict__ vT) {
    const int t = blockIdx.x, h = blockIdx.y, d = threadIdx.x;
    if (h >= 32) {  // V path: write vT[(s*NKV+hv)*HD + d][l]
        int hv = h - 32;
        float val = v[(size_t)t * (NKV * HD) + hv * HD + d];
        int s = t >> 10, l = t & 1023;
        vT[((size_t)(s * NKV + hv) * HD + d) * LSEQ + l] = f2bf(val);
        return;
    }
    const bool isq = (h < 28);
    float val = isq ? q[(size_t)t * (NH * HD) + h * HD + d]
                    : k[(size_t)t * (NKV * HD) + (h - 28) * HD + d];
    float ss = val * val;
#pragma unroll
    for (int off = 32; off >= 1; off >>= 1) ss += __shfl_xor(ss, off, 64);
    __shared__ float wsum[2];
    __shared__ float rowbuf[128];
    if ((threadIdx.x & 63) == 0) wsum[threadIdx.x >> 6] = ss;
    __syncthreads();
    float inv = rsqrtf((wsum[0] + wsum[1]) * (1.f / 128.f) + 1e-6f);
    const float* wn = isq ? ((t & 1) ? qng : qn) : ((t & 1) ? kng : kn);
    float nv = val * inv * wn[d];
    rowbuf[d] = nv;
    __syncthreads();
    float rot = (d < 64) ? -rowbuf[d + 64] : rowbuf[d - 64];
    float o = nv * cosb[(size_t)t * HD + d] + rot * sinb[(size_t)t * HD + d];
    if (isq) q_bf[(size_t)t * (NH * HD) + h * HD + d] = f2bf(o);
    else     k_bf[(size_t)t * (NKV * HD) + (h - 28) * HD + d] = f2bf(o);
}

// ---------------- flash attention ----------------
__global__ __launch_bounds__(256, 2) void attn_fwd(
    const unsigned short* __restrict__ q_bf, const unsigned short* __restrict__ k_bf,
    const unsigned short* __restrict__ vT,
    unsigned short* __restrict__ au, unsigned short* __restrict__ ag) {
    __shared__ unsigned short kt[64 * 128];   // K tile  [kv(64)][d(128)]  swizzled
    __shared__ unsigned short vt[128 * 64];   // V tile  [d(128)][kv(64)]  swizzled
    __shared__ unsigned short pt[4][16 * 64]; // per-wave P [q(16)][kv(64)] swizzled

    const int qbk = blockIdx.x, h = blockIdx.y, s = blockIdx.z;
    const int hk = h / 7;   // GQA group of 7
    const int tid = threadIdx.x, lane = tid & 63, w = tid >> 6;
    const int lr = lane & 15, lkg = lane >> 4;

    bf16x8 qf[4];
    {
        const unsigned short* qp =
            q_bf + ((size_t)(s * LSEQ + qbk * 64 + w * 16 + lr)) * (NH * HD) + h * HD;
#pragma unroll
        for (int kk = 0; kk < 4; kk++) qf[kk] = *(const bf16x8*)(qp + kk * 32 + lkg * 8);
    }

    float m_r[4] = {-1e30f, -1e30f, -1e30f, -1e30f};
    float l_r[4] = {0.f, 0.f, 0.f, 0.f};
    f32x4 accO[8];
#pragma unroll
    for (int dn = 0; dn < 8; dn++) accO[dn] = (f32x4){0.f, 0.f, 0.f, 0.f};

    const float scale = 0.08838834764831843f;   // 1/sqrt(128)
    const int nkt = qbk + 1;

    for (int ktile = 0; ktile < nkt; ++ktile) {
        __syncthreads();
#pragma unroll
        for (int i = 0; i < 4; i++) {
            int o = i * 4096 + tid * 16;
            {   // K: rows 256B = 16 chunks
                int r = o >> 8;
                int sc = ((o >> 4) & 15) ^ (r & 7);
                GLOAD16(k_bf + ((size_t)(s * LSEQ + ktile * 64 + r)) * (NKV * HD) + hk * HD + sc * 8,
                        (char*)kt + o);
            }
            {   // V^T: rows 128B = 8 chunks
                int r = o >> 7;
                int sc = ((o >> 4) & 7) ^ (r & 7);
                GLOAD16(vT + ((size_t)((s * NKV + hk) * HD + r)) * LSEQ + ktile * 64 + sc * 8,
                        (char*)vt + o);
            }
        }
        __syncthreads();

        f32x4 accS[4];
#pragma unroll
        for (int n = 0; n < 4; n++) accS[n] = (f32x4){0.f, 0.f, 0.f, 0.f};
#pragma unroll
        for (int n = 0; n < 4; n++) {
            int r = n * 16 + lr;
#pragma unroll
            for (int kk = 0; kk < 4; kk++) {
                bf16x8 kf = *(const bf16x8*)((const char*)kt + r * 256 +
                                             (((kk * 4 + lkg) ^ (r & 7)) << 4));
                accS[n] = mfma16(qf[kk], kf, accS[n]);
            }
        }
        float mnew[4] = {-1e30f, -1e30f, -1e30f, -1e30f};
#pragma unroll
        for (int n = 0; n < 4; n++) {
            int col = ktile * 64 + n * 16 + lr;
#pragma unroll
            for (int rg = 0; rg < 4; rg++) {
                int row = qbk * 64 + w * 16 + lkg * 4 + rg;
                float sv = accS[n][rg] * scale;
                sv = (col <= row) ? sv : -1e30f;
                accS[n][rg] = sv;
                mnew[rg] = fmaxf(mnew[rg], sv);
            }
        }
#pragma unroll
        for (int off = 1; off < 16; off <<= 1)
#pragma unroll
            for (int rg = 0; rg < 4; rg++)
                mnew[rg] = fmaxf(mnew[rg], __shfl_xor(mnew[rg], off, 64));
        float alpha[4];
#pragma unroll
        for (int rg = 0; rg < 4; rg++) {
            float mc = fmaxf(m_r[rg], mnew[rg]);
            alpha[rg] = __expf(m_r[rg] - mc);
            m_r[rg] = mc;
            l_r[rg] *= alpha[rg];
        }
#pragma unroll
        for (int dn = 0; dn < 8; dn++)
#pragma unroll
            for (int rg = 0; rg < 4; rg++) accO[dn][rg] *= alpha[rg];
        float ls[4] = {0.f, 0.f, 0.f, 0.f};
#pragma unroll
        for (int n = 0; n < 4; n++) {
#pragma unroll
            for (int rg = 0; rg < 4; rg++) {
                float p = __expf(accS[n][rg] - m_r[rg]);
                ls[rg] += p;
                int pr = lkg * 4 + rg;
                *(unsigned short*)((char*)pt[w] + pr * 128 +
                                   (((n * 16 + lr) * 2) ^ ((pr & 7) << 4))) = f2bf(p);
            }
        }
#pragma unroll
        for (int off = 1; off < 16; off <<= 1)
#pragma unroll
            for (int rg = 0; rg < 4; rg++) ls[rg] += __shfl_xor(ls[rg], off, 64);
#pragma unroll
        for (int rg = 0; rg < 4; rg++) l_r[rg] += ls[rg];
#pragma unroll
        for (int kk2 = 0; kk2 < 2; kk2++) {
            bf16x8 pf = *(const bf16x8*)((const char*)pt[w] + lr * 128 +
                                         (((kk2 * 4 + lkg) ^ (lr & 7)) << 4));
#pragma unroll
            for (int dn = 0; dn < 8; dn++) {
                int r2 = dn * 16 + lr;
                bf16x8 vf = *(const bf16x8*)((const char*)vt + r2 * 128 +
                                             (((kk2 * 4 + lkg) ^ (r2 & 7)) << 4));
                accO[dn] = mfma16(pf, vf, accO[dn]);
            }
        }
    }
#pragma unroll
    for (int dn = 0; dn < 8; dn++) {
#pragma unroll
        for (int rg = 0; rg < 4; rg++) {
            int row = qbk * 64 + w * 16 + lkg * 4 + rg;
            int t = s * LSEQ + row;
            unsigned short* dst = ((t & 1) ? ag : au) + (size_t)(t >> 1) * (NH * HD) +
                                  h * HD + dn * 16 + lr;
            *dst = f2bf(accO[dn][rg] / l_r[rg]);
        }
    }
}

// ---------------- host ----------------
extern "C" void kernel_launch(void* const* d_in, const int* in_sizes, int n_in,
                              void* d_out, int out_size, void* d_ws, size_t ws_size,
                              hipStream_t stream) {
    const float* x    = (const float*)d_in[0];
    const float* cosb = (const float*)d_in[1];
    const float* sinb = (const float*)d_in[2];
    const float* wq   = (const float*)d_in[3];
    const float* bq   = (const float*)d_in[4];
    const float* wk   = (const float*)d_in[5];
    const float* bk   = (const float*)d_in[6];
    const float* wv   = (const float*)d_in[7];
    const float* bv   = (const float*)d_in[8];
    const float* wo   = (const float*)d_in[9];
    const float* wqg  = (const float*)d_in[10];
    const float* bqg  = (const float*)d_in[11];
    const float* wkg  = (const float*)d_in[12];
    const float* bkg  = (const float*)d_in[13];
    const float* wvg  = (const float*)d_in[14];
    const float* bvg  = (const float*)d_in[15];
    const float* wog  = (const float*)d_in[16];
    const float* qn   = (const float*)d_in[17];
    const float* kn   = (const float*)d_in[18];
    const float* qng  = (const float*)d_in[19];
    const float* kng  = (const float*)d_in[20];
    float* out = (float*)d_out;

    char* ws = (char*)d_ws;
    size_t off = 0;
    auto alloc = [&](size_t bytes) -> char* {
        char* p = ws + off;
        off += (bytes + 255) & ~(size_t)255;
        return p;
    };
    const size_t WQ_E = (size_t)3584 * 3584;
    const size_t WK_E = (size_t)512 * 3584;
    unsigned short* wqb  = (unsigned short*)alloc(WQ_E * 2);
    unsigned short* wqgb = (unsigned short*)alloc(WQ_E * 2);
    unsigned short* wob  = (unsigned short*)alloc(WQ_E * 2);
    unsigned short* wogb = (unsigned short*)alloc(WQ_E * 2);
    unsigned short* wkb  = (unsigned short*)alloc(WK_E * 2);
    unsigned short* wkgb = (unsigned short*)alloc(WK_E * 2);
    unsigned short* wvb  = (unsigned short*)alloc(WK_E * 2);
    unsigned short* wvgb = (unsigned short*)alloc(WK_E * 2);
    unsigned short* xu   = (unsigned short*)alloc((size_t)2048 * HID * 2);
    unsigned short* xg   = (unsigned short*)alloc((size_t)2048 * HID * 2);
    float* qf32 = (float*)alloc((size_t)T_TOK * (NH * HD) * 4);
    float* kf32 = (float*)alloc((size_t)T_TOK * (NKV * HD) * 4);
    float* vf32 = (float*)alloc((size_t)T_TOK * (NKV * HD) * 4);
    unsigned short* q_bf = (unsigned short*)alloc((size_t)T_TOK * (NH * HD) * 2);
    unsigned short* k_bf = (unsigned short*)alloc((size_t)T_TOK * (NKV * HD) * 2);
    unsigned short* vTb  = (unsigned short*)alloc((size_t)SEG * NKV * HD * LSEQ * 2);
    unsigned short* au = (unsigned short*)qf32;   // aliases dead qf32
    unsigned short* ag = au + (size_t)2048 * (NH * HD);

    if (ws_size < off) return;

    cvt_x_split<<<T_TOK * (HID / 4) / 256, 256, 0, stream>>>(x, xu, xg);
    cvt_f32_bf16<<<(int)(WQ_E / 4 / 256), 256, 0, stream>>>(wq,  wqb,  (int)(WQ_E / 4));
    cvt_f32_bf16<<<(int)(WQ_E / 4 / 256), 256, 0, stream>>>(wqg, wqgb, (int)(WQ_E / 4));
    cvt_f32_bf16<<<(int)(WQ_E / 4 / 256), 256, 0, stream>>>(wo,  wob,  (int)(WQ_E / 4));
    cvt_f32_bf16<<<(int)(WQ_E / 4 / 256), 256, 0, stream>>>(wog, wogb, (int)(WQ_E / 4));
    cvt_f32_bf16<<<(int)(WK_E / 4 / 256), 256, 0, stream>>>(wk,  wkb,  (int)(WK_E / 4));
    cvt_f32_bf16<<<(int)(WK_E / 4 / 256), 256, 0, stream>>>(wkg, wkgb, (int)(WK_E / 4));
    cvt_f32_bf16<<<(int)(WK_E / 4 / 256), 256, 0, stream>>>(wv,  wvb,  (int)(WK_E / 4));
    cvt_f32_bf16<<<(int)(WK_E / 4 / 256), 256, 0, stream>>>(wvg, wvgb, (int)(WK_E / 4));

    qkv_gemm8<<<dim3(16, 18), 512, 0, stream>>>(xu, xg, wqb, wkb, wvb, wqgb, wkgb, wvgb,
                                                bq, bk, bv, bqg, bkg, bvg, qf32, kf32, vf32);
    normrope<<<dim3(T_TOK, 36), 128, 0, stream>>>(qf32, kf32, vf32, cosb, sinb,
                                                  qn, kn, qng, kng, q_bf, k_bf, vTb);
    attn_fwd<<<dim3(16, NH, SEG), 256, 0, stream>>>(q_bf, k_bf, vTb, au, ag);
    oproj_gemm8<<<dim3(16, 14), 512, 0, stream>>>(au, ag, wob, wogb, out);
}